// Round 4
// baseline (816.129 us; speedup 1.0000x reference)
//
#include <hip/hip_runtime.h>

// Potts energy kernel for MI355X.
// B=2, N=4096, K=48, Q=20.
// Outputs (flat concat): U (B,) then U_i (B,N,Q), fp32.
//
// R7: dense-lockstep-sweep experiment. R3/R4/R6 (stream, batched stream,
// 503MB scatter) all pinned at ~796 total -> the J-pass time is invariant
// under schedule AND byte count. Theory (A): ~1000 concurrent block-private
// 75KB streams thrash DRAM rows; the 6.3TB/s fill is a single dense sweep.
// This version is fill-shaped: 2048x256 = 524288 threads = exactly the
// device's 8192-wave capacity, all resident, grid-stride so the whole device
// reads one contiguous ~8MB moving window (75 exact iterations).
// Node-association decoupled: pre-kernel builds Sj[b,n,k]; sweep writes each
// (node,k,q) row's single selected element to ws2[mk*20+q] (plain store, no
// atomics -- exactly one of each 5-float4 group is selected, every slot
// written every run); dense fold kernel produces U_i + node_c; reduce -> U.
// If this doesn't move dur_us, the window is harness-floored (theory B) and
// we are at the roofline.

constexpr int Bc = 2;
constexpr int Nc = 4096;
constexpr int Kc = 48;
constexpr int Qc = 20;
constexpr int NODES   = Bc * Nc;                 // 8192
constexpr int NODE_F4 = Kc * Qc * Qc / 4;        // 4800
constexpr long long TOT_F4 = (long long)NODES * NODE_F4;   // 39,321,600
constexpr int SWEEP_BLOCKS = 2048;
constexpr int SWEEP_TPB    = 256;
constexpr int G     = SWEEP_BLOCKS * SWEEP_TPB;  // 524288
constexpr int ITERS = (int)(TOT_F4 / G);         // 75 exact

// workspace layout (float offsets); ws is >= 2.4GB (harness fill evidence)
constexpr size_t WS_SJ = 0;              // Sj: Bc*Nc*Kc ints = 393216
constexpr size_t WS_NC = 512 * 1024;     // node_c: 8192 floats at +2MB
constexpr size_t WS_W2 = 1024 * 1024;    // ws2: NODES*Kc*Qc = 7,864,320 floats at +4MB

// Sj[g] = S[b, edge_idx[g]]   g = (b,n,k) flat, 393216 = 1536*256 exact
__global__ __launch_bounds__(256) void sj_gather_kernel(
    const int* __restrict__ S, const int* __restrict__ edge_idx,
    int* __restrict__ Sj)
{
    const int g = blockIdx.x * 256 + threadIdx.x;
    const int e = edge_idx[g];
    const int b = (g >= Nc * Kc) ? 1 : 0;          // Bc == 2
    Sj[g] = S[b * Nc + e];
}

// Dense sweep over all of J. m = float4 index; 100 f4 per (node,k) row-block,
// 5 f4 per (node,k,q) row. Selected element (s == Sj) -> ws2[m/5] = mk*20+q.
__global__ __launch_bounds__(SWEEP_TPB, 8) void sweep_kernel(
    const float* __restrict__ J, const int* __restrict__ Sj,
    float* __restrict__ w2)
{
    const int g0 = blockIdx.x * SWEEP_TPB + threadIdx.x;
    const float4* Jf = (const float4*)J;
    #pragma unroll 5
    for (int i = 0; i < ITERS; ++i) {
        const int m = g0 + i * G;          // < 2^31
        float4 v = Jf[m];
        int mk = m / 100;                  // (node,k) flat index, magic mul
        int r  = m - mk * 100;
        int q  = r / 5;
        int s0 = (r - q * 5) << 2;
        int d  = Sj[mk] - s0;              // L2-resident 1.5MB table
        if ((unsigned)d < 4u) {
            float val = (d == 0) ? v.x : (d == 1) ? v.y : (d == 2) ? v.z : v.w;
            w2[mk * 20 + q] = val;         // == m/5; plain coalesced-ish store
        }
    }
}

// Fold ws2 (960 contiguous floats per node) into U_i and node_c.
__global__ __launch_bounds__(64) void node_sum_kernel(
    const float* __restrict__ w2, const float* __restrict__ h,
    const int*   __restrict__ S,  float* __restrict__ U_i_out,
    float*       __restrict__ node_c)
{
    const int node = blockIdx.x;
    const int l    = threadIdx.x;
    const int s_i  = S[node];
    if (l < Qc) {
        const float* p = w2 + (size_t)node * (Kc * Qc) + l;
        float ji = 0.0f;
        #pragma unroll
        for (int k = 0; k < Kc; ++k) ji += p[k * Qc];
        const float ui = h[node * Qc + l] + ji;
        U_i_out[node * Qc + l] = ui;
        if (l == s_i) node_c[node] = ui - 0.5f * ji;
    }
}

__global__ __launch_bounds__(256) void potts_reduce_kernel(
    const float* __restrict__ node_c, float* __restrict__ U)
{
    const int b   = blockIdx.x;
    const int tid = threadIdx.x;
    float s = 0.0f;
    for (int i = tid; i < Nc; i += 256) s += node_c[b * Nc + i];
    #pragma unroll
    for (int off = 32; off > 0; off >>= 1) s += __shfl_down(s, off, 64);
    __shared__ float ws[4];
    if ((tid & 63) == 0) ws[tid >> 6] = s;
    __syncthreads();
    if (tid == 0) U[b] = ws[0] + ws[1] + ws[2] + ws[3];
}

extern "C" void kernel_launch(void* const* d_in, const int* in_sizes, int n_in,
                              void* d_out, int out_size, void* d_ws, size_t ws_size,
                              hipStream_t stream) {
    const int*   S        = (const int*)  d_in[0];
    const float* h        = (const float*)d_in[1];
    const float* J        = (const float*)d_in[2];
    const int*   edge_idx = (const int*)  d_in[3];

    float* out    = (float*)d_out;
    float* U      = out;        // 2 floats
    float* U_i    = out + Bc;   // B*N*Q floats

    float* wsf    = (float*)d_ws;
    int*   Sj     = (int*)  (wsf + WS_SJ);
    float* node_c =          wsf + WS_NC;
    float* w2     =          wsf + WS_W2;

    sj_gather_kernel<<<Bc * Nc * Kc / 256, 256, 0, stream>>>(S, edge_idx, Sj);
    sweep_kernel<<<SWEEP_BLOCKS, SWEEP_TPB, 0, stream>>>(J, Sj, w2);
    node_sum_kernel<<<NODES, 64, 0, stream>>>(w2, h, S, U_i, node_c);
    potts_reduce_kernel<<<Bc, 256, 0, stream>>>(node_c, U);
}

// Round 6
// 760.433 us; speedup vs baseline: 1.0732x; 1.0732x over previous
//
#include <hip/hip_runtime.h>
#include <hip/hip_bf16.h>

// Potts energy kernel for MI355X.
// B=2, N=4096, K=48, Q=20.
// Outputs (flat concat): U (B,) then U_i (B,N,Q), fp32.
//
// R8b: single-variable experiment on the read path (compile-fixed retry).
// Five schedules (R3-R7: interleaved stream, batch-issued, one-wave
// copy-shaped, 503MB scatter, fill-shaped dense lockstep sweep at max
// occupancy) ALL pin the 629 MB J read at ~1.63 TB/s, while the harness's
// own 2.4 GB fill WRITES at 6.3 TB/s in the same window.
// Schedule/MLP/byte-count are eliminated. Remaining suspect: the
// read-allocate path (TCP -> L2 allocate -> L3 lookup/allocate) choking a
// never-hitting 629 MB stream. This is R4 verbatim with ALL J loads
// switched to __builtin_nontemporal_load (nt bits: bypass cache allocation).
// NOTE: the builtin rejects HIP_vector_type structs -> use a native clang
// ext_vector_type(4) float vector for the loads.

constexpr int Bc = 2;
constexpr int Nc = 4096;
constexpr int Kc = 48;
constexpr int Qc = 20;
constexpr int NODE_FLOATS = Kc * Qc * Qc;      // 19200
constexpr int NODE_F4     = NODE_FLOATS / 4;   // 4800
constexpr int TPB         = 320;               // 5 waves; 4800 % 320 == 0
constexpr int NITER       = NODE_F4 / TPB;     // 15

typedef float f32x4 __attribute__((ext_vector_type(4)));

__global__ __launch_bounds__(TPB) void potts_node_kernel(
    const int*   __restrict__ S,
    const float* __restrict__ h,
    const float* __restrict__ J,
    const int*   __restrict__ edge_idx,
    float*       __restrict__ U_i_out,   // (B*N*Q)
    float*       __restrict__ node_c)    // (B*N) per-node scalar contribution
{
    const int node = blockIdx.x;          // 0 .. B*N-1
    const int b    = node >> 12;          // node / N (N=4096)
    const int tid  = threadIdx.x;

    __shared__ float Jl[Qc];
    __shared__ int   sj[Kc];
    __shared__ int   s_i_sh;

    // Phase 1: issue ALL 15 coalesced 16B loads back-to-back, nontemporal.
    const f32x4* Jb = (const f32x4*)(J + (size_t)node * NODE_FLOATS);
    f32x4 v[NITER];
    #pragma unroll
    for (int j = 0; j < NITER; ++j) v[j] = __builtin_nontemporal_load(&Jb[tid + j * TPB]);
    // Pin the load cluster: nothing may be scheduled above this point.
    __builtin_amdgcn_sched_barrier(0);

    // Phase 2: prologue gather overlaps the J-load latency.
    if (tid < Qc) Jl[tid] = 0.0f;
    if (tid < Kc) {
        int e = edge_idx[node * Kc + tid];
        sj[tid] = S[b * Nc + e];
    }
    if (tid == 0) s_i_sh = S[node];
    __syncthreads();   // drains vmcnt+lgkmcnt: all v[] and sj[] ready

    // Phase 3: pure VALU/LDS processing on register data.
    #pragma unroll
    for (int j = 0; j < NITER; ++j) {
        const int m = tid + j * TPB;
        // flat float index f = 4*m ; f = k*400 + q*20 + s ; s0 in {0,4,8,12,16}
        int k  = m / 100;              // 100 float4 per k
        int r  = m - k * 100;
        int q  = r / 5;
        int s0 = (r - q * 5) << 2;
        int d  = sj[k] - s0;
        if ((unsigned)d < 4u) {
            f32x4 vv = v[j];
            float val = (d == 0) ? vv.x : (d == 1) ? vv.y : (d == 2) ? vv.z : vv.w;
            atomicAdd(&Jl[q], val);
        }
    }
    __syncthreads();

    if (tid < Qc) {
        float ji = Jl[tid];
        float ui = h[node * Qc + tid] + ji;
        U_i_out[node * Qc + tid] = ui;
        if (tid == s_i_sh) {
            // U contribution: (h[s]+J_i[s]) - 0.5*J_i[s] = ui - 0.5*ji
            node_c[node] = ui - 0.5f * ji;
        }
    }
}

__global__ __launch_bounds__(256) void potts_reduce_kernel(
    const float* __restrict__ node_c, float* __restrict__ U)
{
    const int b   = blockIdx.x;
    const int tid = threadIdx.x;
    float s = 0.0f;
    for (int i = tid; i < Nc; i += 256) s += node_c[b * Nc + i];
    #pragma unroll
    for (int off = 32; off > 0; off >>= 1) s += __shfl_down(s, off, 64);
    __shared__ float ws[4];
    if ((tid & 63) == 0) ws[tid >> 6] = s;
    __syncthreads();
    if (tid == 0) U[b] = ws[0] + ws[1] + ws[2] + ws[3];
}

extern "C" void kernel_launch(void* const* d_in, const int* in_sizes, int n_in,
                              void* d_out, int out_size, void* d_ws, size_t ws_size,
                              hipStream_t stream) {
    const int*   S        = (const int*)  d_in[0];
    const float* h        = (const float*)d_in[1];
    const float* J        = (const float*)d_in[2];
    const int*   edge_idx = (const int*)  d_in[3];

    float* out    = (float*)d_out;
    float* U      = out;        // 2 floats
    float* U_i    = out + Bc;   // B*N*Q floats
    float* node_c = (float*)d_ws;

    potts_node_kernel<<<Bc * Nc, TPB, 0, stream>>>(S, h, J, edge_idx, U_i, node_c);
    potts_reduce_kernel<<<Bc, 256, 0, stream>>>(node_c, U);
}